// Round 1
// baseline (834.666 us; speedup 1.0000x reference)
//
#include <hip/hip_runtime.h>
#include <hip/hip_bf16.h>
#include <stdint.h>

// Problem constants (from reference setup_inputs)
#define N_NODES 50000
#define NE      400000
#define HDIM    128
#define MPAD    50048     // 391 * 128, zero-padded rows for clean GEMM tiling
#define TE      128       // edges per block in edge kernel

typedef __attribute__((ext_vector_type(8))) short bf16x8;   // 8 bf16 in 4 VGPRs
typedef __attribute__((ext_vector_type(4))) float f32x4;

__device__ __forceinline__ ushort f2b(float f) {
    uint32_t u = __float_as_uint(f);
    uint32_t r = (u + 0x7fffu + ((u >> 16) & 1u)) >> 16;   // RTNE
    return (ushort)r;
}
__device__ __forceinline__ float b2f(ushort s) {
    return __uint_as_float(((uint32_t)s) << 16);
}
__device__ __forceinline__ float silu_f(float x) {
    return x / (1.f + __expf(-x));
}
__device__ __forceinline__ float tanh_f(float x) {
    // stable: x>>0 -> 1, x<<0 -> -1
    return 1.f - 2.f / (__expf(2.f * x) + 1.f);
}

// ---------------------------------------------------------------------------
// out[0:NH) = x, out[NH:2NH) = pe   (accumulation targets for atomics)
__global__ void k_init_out(const float4* __restrict__ x, const float4* __restrict__ pe,
                           float4* __restrict__ out) {
    int i = blockIdx.x * 256 + threadIdx.x;
    const int nh4 = N_NODES * HDIM / 4;
    if (i < nh4) out[i] = x[i];
    else out[i] = pe[i - nh4];
}

// Xc[row, 0:128] = bf16(x[row]), Xc[row,128:256] = bf16(pe[row]); pad rows = 0
__global__ void k_prep_xc(const float* __restrict__ x, const float* __restrict__ pe,
                          ushort* __restrict__ Xc) {
    int row = blockIdx.x;       // 0..MPAD-1
    int col = threadIdx.x;      // 0..255
    float v = 0.f;
    if (row < N_NODES) v = (col < HDIM) ? x[row * HDIM + col] : pe[row * HDIM + col - HDIM];
    Xc[row * 256 + col] = f2b(v);
}

// Build transposed bf16 weights + dist-row extracts.
// WcT[n][k]: n<128 -> W1[k][n]; n<256 -> W1[256+k][n-128];
//            n<384 -> (k<128?0:Wp1[k-128][n-256]); else (k<128?0:Wp1[k][n-384])
__global__ void k_prep_w(const float* __restrict__ W1, const float* __restrict__ Wp1,
                         const float* __restrict__ W2, const float* __restrict__ Wp2,
                         ushort* __restrict__ WcT, ushort* __restrict__ W2t,
                         ushort* __restrict__ Wp2t, float* __restrict__ w1d,
                         float* __restrict__ wp1d) {
    int b = blockIdx.x, t = threadIdx.x;
    if (b < 512) {
        int n = b, k = t;
        float v;
        if (n < 128)       v = W1[k * HDIM + n];
        else if (n < 256)  v = W1[(256 + k) * HDIM + (n - 128)];
        else if (n < 384)  v = (k < 128) ? 0.f : Wp1[(k - 128) * HDIM + (n - 256)];
        else               v = (k < 128) ? 0.f : Wp1[k * HDIM + (n - 384)];
        WcT[n * 256 + k] = f2b(v);
    } else if (b < 640) {
        if (t < 128) { int n = b - 512; W2t[n * HDIM + t] = f2b(W2[t * HDIM + n]); }
    } else if (b < 768) {
        if (t < 128) { int n = b - 640; Wp2t[n * HDIM + t] = f2b(Wp2[t * HDIM + n]); }
    } else {
        if (t < 128) w1d[t] = W1[512 * HDIM + t];
        else if (t < 256) wp1d[t - 128] = Wp1[256 * HDIM + (t - 128)];
    }
}

// ---------------------------------------------------------------------------
// Pn[MPAD,512] bf16 = Xc[MPAD,256] @ Wc[256,512], via WcT.  128x128 block tile,
// 4 waves each computing a 64x64 quadrant with 4x4 16x16x32 MFMA fragments.
__global__ __launch_bounds__(256) void k_node_gemm(const ushort* __restrict__ Xc,
                                                   const ushort* __restrict__ WcT,
                                                   ushort* __restrict__ Pn) {
    const int m0 = blockIdx.y * 128;
    const int n0 = blockIdx.x * 128;
    const int wave = threadIdx.x >> 6;
    const int lane = threadIdx.x & 63;
    const int l15 = lane & 15, quad = lane >> 4;
    const int qr = (wave >> 1) * 64, qc = (wave & 1) * 64;

    f32x4 acc[4][4];
#pragma unroll
    for (int i = 0; i < 4; i++)
#pragma unroll
        for (int j = 0; j < 4; j++) acc[i][j] = (f32x4){0.f, 0.f, 0.f, 0.f};

#pragma unroll
    for (int s = 0; s < 8; s++) {
        const int k0 = s * 32 + quad * 8;
        bf16x8 a[4], b[4];
#pragma unroll
        for (int rg = 0; rg < 4; rg++) {
            int row = m0 + qr + rg * 16 + l15;
            a[rg] = *(const bf16x8*)(Xc + row * 256 + k0);
        }
#pragma unroll
        for (int cg = 0; cg < 4; cg++) {
            int nn = n0 + qc + cg * 16 + l15;
            b[cg] = *(const bf16x8*)(WcT + nn * 256 + k0);
        }
#pragma unroll
        for (int rg = 0; rg < 4; rg++)
#pragma unroll
            for (int cg = 0; cg < 4; cg++)
                acc[rg][cg] = __builtin_amdgcn_mfma_f32_16x16x32_bf16(a[rg], b[cg], acc[rg][cg], 0, 0, 0);
    }

#pragma unroll
    for (int rg = 0; rg < 4; rg++)
#pragma unroll
        for (int cg = 0; cg < 4; cg++) {
            int col = n0 + qc + cg * 16 + l15;
            int rowb = m0 + qr + rg * 16 + quad * 4;
#pragma unroll
            for (int r = 0; r < 4; r++)
                Pn[(size_t)(rowb + r) * 512 + col] = f2b(acc[rg][cg][r]);
        }
}

// ---------------------------------------------------------------------------
// Edge kernel: per block, TE=128 edges.  For each path p (0=msg/silu, 1=pe/tanh):
//   h1[e] = act(Pn[s, p*256 + c] + Pn[r, p*256+128 + c] + dist*wd[c] + b1[c])
//   msg[e] = act(h1 @ W2t^T + b2);  atomicAdd into out[p*NH + rec*128 + col].
__global__ __launch_bounds__(256) void k_edge(
    const ushort* __restrict__ Pn, const float* __restrict__ pos,
    const int* __restrict__ eidx,
    const float* __restrict__ w1d, const float* __restrict__ b1,
    const ushort* __restrict__ W2t, const float* __restrict__ b2,
    const float* __restrict__ wp1d, const float* __restrict__ bp1,
    const ushort* __restrict__ Wp2t, const float* __restrict__ bp2,
    float* __restrict__ out)
{
    // +8 ushort pad per row: 272B stride -> 2-way LDS bank aliasing only (free)
    __shared__ __align__(16) ushort sA[TE][136];
    __shared__ __align__(16) ushort sW[128][136];
    __shared__ float sDist[TE];
    __shared__ int sSend[TE], sRec[TE];

    const int tid = threadIdx.x;
    const int e0 = blockIdx.x * TE;

    if (tid < TE) {
        int e = e0 + tid;
        int s = eidx[e], r = eidx[NE + e];
        float dx = pos[s * 3 + 0] - pos[r * 3 + 0];
        float dy = pos[s * 3 + 1] - pos[r * 3 + 1];
        float dz = pos[s * 3 + 2] - pos[r * 3 + 2];
        sDist[tid] = sqrtf(dx * dx + dy * dy + dz * dz);
        sSend[tid] = s; sRec[tid] = r;
    }
    __syncthreads();

    const int wave = tid >> 6, lane = tid & 63;
    const int l15 = lane & 15, quad = lane >> 4;

    for (int p = 0; p < 2; p++) {
        const ushort* Wt = p ? Wp2t : W2t;
        const float* wd  = p ? wp1d : w1d;
        const float* bb1 = p ? bp1  : b1;
        const float* bb2 = p ? bp2  : b2;

        // stage transposed second-layer weight into LDS
        for (int i = tid; i < 128 * 16; i += 256) {
            int row = i >> 4, c8 = (i & 15) * 8;
            *(uint4*)&sW[row][c8] = *(const uint4*)(Wt + row * HDIM + c8);
        }
        // gather Pn halves, fuse first layer + activation, store bf16 tile
        for (int i = tid; i < TE * 16; i += 256) {
            int e = i >> 4, c8 = (i & 15) * 8;
            int s = sSend[e], r = sRec[e];
            float d = sDist[e];
            uint4 us = *(const uint4*)(Pn + (size_t)s * 512 + p * 256 + c8);
            uint4 ur = *(const uint4*)(Pn + (size_t)r * 512 + p * 256 + 128 + c8);
            const ushort* pus = (const ushort*)&us;
            const ushort* pur = (const ushort*)&ur;
            ushort res[8];
#pragma unroll
            for (int j = 0; j < 8; j++) {
                int ch = c8 + j;
                float v = b2f(pus[j]) + b2f(pur[j]) + d * wd[ch] + bb1[ch];
                v = p ? tanh_f(v) : silu_f(v);
                res[j] = f2b(v);
            }
            *(uint4*)&sA[e][c8] = *(const uint4*)res;
        }
        __syncthreads();

        // MFMA: wave w covers edge rows [w*32, w*32+32), all 128 output cols
        f32x4 acc[2][8];
#pragma unroll
        for (int rg = 0; rg < 2; rg++)
#pragma unroll
            for (int cg = 0; cg < 8; cg++) acc[rg][cg] = (f32x4){0.f, 0.f, 0.f, 0.f};

#pragma unroll
        for (int s4 = 0; s4 < 4; s4++) {
            int k0 = s4 * 32 + quad * 8;
            bf16x8 a0 = *(const bf16x8*)&sA[wave * 32 + l15][k0];
            bf16x8 a1 = *(const bf16x8*)&sA[wave * 32 + 16 + l15][k0];
#pragma unroll
            for (int cg = 0; cg < 8; cg++) {
                bf16x8 b = *(const bf16x8*)&sW[cg * 16 + l15][k0];
                acc[0][cg] = __builtin_amdgcn_mfma_f32_16x16x32_bf16(a0, b, acc[0][cg], 0, 0, 0);
                acc[1][cg] = __builtin_amdgcn_mfma_f32_16x16x32_bf16(a1, b, acc[1][cg], 0, 0, 0);
            }
        }

        // epilogue: bias + activation + atomic scatter to receiving nodes
        float* outp = out + (size_t)p * N_NODES * HDIM;
#pragma unroll
        for (int rg = 0; rg < 2; rg++) {
            int rowb = wave * 32 + rg * 16 + quad * 4;
#pragma unroll
            for (int cg = 0; cg < 8; cg++) {
                int col = cg * 16 + l15;
                float bias = bb2[col];
#pragma unroll
                for (int r = 0; r < 4; r++) {
                    float v = acc[rg][cg][r] + bias;
                    v = p ? tanh_f(v) : silu_f(v);
                    atomicAdd(outp + (size_t)sRec[rowb + r] * HDIM + col, v);
                }
            }
        }
        __syncthreads();   // protect sA/sW rewrite in next path
    }
}

// ---------------------------------------------------------------------------
extern "C" void kernel_launch(void* const* d_in, const int* in_sizes, int n_in,
                              void* d_out, int out_size, void* d_ws, size_t ws_size,
                              hipStream_t stream) {
    const float* x   = (const float*)d_in[0];
    const float* pos = (const float*)d_in[1];
    const float* pe  = (const float*)d_in[2];
    const int* eidx  = (const int*)d_in[3];
    const float* W1  = (const float*)d_in[4];
    const float* b1  = (const float*)d_in[5];
    const float* W2  = (const float*)d_in[6];
    const float* b2  = (const float*)d_in[7];
    const float* Wp1 = (const float*)d_in[8];
    const float* bp1 = (const float*)d_in[9];
    const float* Wp2 = (const float*)d_in[10];
    const float* bp2 = (const float*)d_in[11];
    float* out = (float*)d_out;

    // workspace carve-up (all offsets 256B aligned)
    char* w = (char*)d_ws;
    ushort* Xc   = (ushort*)(w);                                  // MPAD*256*2 = 25,624,576
    ushort* Pn   = (ushort*)(w + 25624576);                       // MPAD*512*2 = 51,249,152
    ushort* WcT  = (ushort*)(w + 25624576 + 51249152);            // 512*256*2  = 262,144
    ushort* W2t  = (ushort*)(w + 25624576 + 51249152 + 262144);   // 32,768
    ushort* Wp2t = (ushort*)(w + 25624576 + 51249152 + 262144 + 32768);
    float*  w1d  = (float*)(w + 25624576 + 51249152 + 262144 + 65536);
    float*  wp1d = (float*)(w + 25624576 + 51249152 + 262144 + 65536 + 2048);

    // prep
    k_prep_w<<<769, 256, 0, stream>>>(W1, Wp1, W2, Wp2, WcT, W2t, Wp2t, w1d, wp1d);
    k_prep_xc<<<MPAD, 256, 0, stream>>>(x, pe, Xc);
    k_init_out<<<(2 * N_NODES * HDIM / 4 + 255) / 256, 256, 0, stream>>>(
        (const float4*)x, (const float4*)pe, (float4*)out);

    // node-level GEMM: Pn = Xc @ Wc
    dim3 ggrid(4, MPAD / 128);
    k_node_gemm<<<ggrid, 256, 0, stream>>>(Xc, WcT, Pn);

    // edge pipeline + scatter
    k_edge<<<NE / TE, 256, 0, stream>>>(Pn, pos, eidx, w1d, b1, W2t, b2,
                                        wp1d, bp1, Wp2t, bp2, out);
}